// Round 6
// baseline (270.229 us; speedup 1.0000x reference)
//
#include <hip/hip_runtime.h>

typedef __bf16 bf16x8 __attribute__((ext_vector_type(8)));
typedef __bf16 bf16x4 __attribute__((ext_vector_type(4)));
typedef _Float16 half4 __attribute__((ext_vector_type(4)));
typedef _Float16 half8 __attribute__((ext_vector_type(8)));
typedef float f32x4 __attribute__((ext_vector_type(4)));

#define MFMA_BF16(a, b, c) __builtin_amdgcn_mfma_f32_16x16x32_bf16(a, b, c, 0, 0, 0)
#define MFMA_F16K32(a, b, c) __builtin_amdgcn_mfma_f32_16x16x32_f16(a, b, c, 0, 0, 0)
#define MFMA_F16K16(a, b, c) __builtin_amdgcn_mfma_f32_16x16x16f16(a, b, c, 0, 0, 0)
#define EXP2F(x) __builtin_amdgcn_exp2f(x)

constexpr int NSEQ = 2048, DIM = 1024;
constexpr int MROWS = 4096;
constexpr float QSCALE = 11.5415603271f;  // 8 * log2(e)

__device__ __forceinline__ void split_bf16(float x, __bf16& h, __bf16& l) {
  h = (__bf16)x;
  l = (__bf16)(x - (float)h);
}

__device__ __forceinline__ void ld_lds16(void* lds, const void* g) {
  __builtin_amdgcn_global_load_lds(
      (const __attribute__((address_space(1))) void*)g,
      (__attribute__((address_space(3))) void*)lds, 16, 0, 0);
}

// ---------------------------------------------------------------------------
// Merged prep: blocks 0..1023 transpose weights (64x64 f32 tiles);
// blocks 1024..3071 split x into bf16 hi/lo.
// ---------------------------------------------------------------------------
__global__ __launch_bounds__(256) void prep(
    const float* __restrict__ w_q, const float* __restrict__ w_vk,
    const float* __restrict__ w_out, const float* __restrict__ x,
    __bf16* __restrict__ WTh, __bf16* __restrict__ WTl,
    _Float16* __restrict__ WoT, __bf16* __restrict__ xh,
    __bf16* __restrict__ xl) {
  const int bid = blockIdx.x;
  const int t = threadIdx.x;
  if (bid >= 1024) {  // ---- split_x ----
    const size_t i = ((size_t)(bid - 1024) * 256 + t) * 8;
    float4 a = *(const float4*)(x + i), b2 = *(const float4*)(x + i + 4);
    float v[8] = {a.x, a.y, a.z, a.w, b2.x, b2.y, b2.z, b2.w};
    bf16x8 h, l;
#pragma unroll
    for (int j = 0; j < 8; ++j) {
      __bf16 hh, ll;
      split_bf16(v[j], hh, ll);
      h[j] = hh; l[j] = ll;
    }
    *(bf16x8*)(xh + i) = h;
    *(bf16x8*)(xl + i) = l;
    return;
  }
  // ---- weight transpose ----
  __shared__ float T[64][65];
  const int bx = bid & 63, k0 = (bid >> 6) * 64;
  const float* src;
  int srcN, n0, dstrow, mode;
  float scale;
  if (bx < 16) {
    src = w_q; srcN = 1024; n0 = bx * 64; dstrow = n0; scale = QSCALE; mode = 0;
  } else if (bx < 48) {
    src = w_vk; srcN = 2048; n0 = (bx - 16) * 64; dstrow = 1024 + n0;
    scale = 1.0f; mode = 0;
  } else {
    src = w_out; srcN = 1024; n0 = (bx - 48) * 64; dstrow = n0;
    scale = 1.0f; mode = 1;
  }
  {
    const int r = t >> 2, c4 = (t & 3) * 16;
    const float* s = src + (size_t)(k0 + r) * srcN + n0 + c4;
    float4 v0 = ((const float4*)s)[0], v1 = ((const float4*)s)[1],
           v2 = ((const float4*)s)[2], v3 = ((const float4*)s)[3];
    *(float4*)&T[r][c4 + 0] = v0;  *(float4*)&T[r][c4 + 4] = v1;
    *(float4*)&T[r][c4 + 8] = v2;  *(float4*)&T[r][c4 + 12] = v3;
  }
  __syncthreads();
  const int rn = t >> 2, kc = (t & 3) * 16;
  if (mode == 0) {
    bf16x8 hv[2], lv[2];
#pragma unroll
    for (int half = 0; half < 2; ++half)
#pragma unroll
      for (int j = 0; j < 8; ++j) {
        float v = T[kc + half * 8 + j][rn] * scale;
        __bf16 h, l;
        split_bf16(v, h, l);
        hv[half][j] = h; lv[half][j] = l;
      }
    __bf16* dh = WTh + (size_t)(dstrow + rn) * 1024 + k0 + kc;
    *(bf16x8*)dh = hv[0]; *(bf16x8*)(dh + 8) = hv[1];
    if (dstrow < 2048) {
      __bf16* dl = WTl + (size_t)(dstrow + rn) * 1024 + k0 + kc;
      *(bf16x8*)dl = lv[0]; *(bf16x8*)(dl + 8) = lv[1];
    }
  } else {
    half8 hv[2];
#pragma unroll
    for (int half = 0; half < 2; ++half)
#pragma unroll
      for (int j = 0; j < 8; ++j)
        hv[half][j] = (_Float16)T[kc + half * 8 + j][rn];
    _Float16* d = WoT + (size_t)(n0 + rn) * 1024 + k0 + kc;
    *(half8*)d = hv[0]; *(half8*)(d + 8) = hv[1];
  }
}

// ---------------------------------------------------------------------------
// Fused q/k/v projection — double-buffered LDS, ONE barrier per K-iter.
// kind 0: q -> qTh/qTl transposed [col][token]; 1: k -> KH/KL; 2: v -> VT
// (fp16, single product xh*wh).
// ---------------------------------------------------------------------------
__global__ __launch_bounds__(256, 2) void proj5(
    const __bf16* __restrict__ xh, const __bf16* __restrict__ xl,
    const __bf16* __restrict__ WTh, const __bf16* __restrict__ WTl,
    __bf16* __restrict__ qTh, __bf16* __restrict__ qTl,
    __bf16* __restrict__ KH, __bf16* __restrict__ KL,
    _Float16* __restrict__ VT) {
  __shared__ __align__(16) char smem[65536];  // 2 bufs x (Xh|Xl|Bh|Bl) 8KB each
  const int t = threadIdx.x;
  const int lane = t & 63, wave = t >> 6, quad = lane >> 4, lq = lane & 15;
  const int bn = blockIdx.x * 128, bm = blockIdx.y * 128;
  const int kind = bn >> 10;
  const int wm = (wave >> 1) * 64, wn = (wave & 1) * 64;

  const int srow = lane >> 2;                // 0..15
  const int schk = (lane & 3) ^ (srow & 3);  // 16B chunk
  const __bf16* xh_g = xh + (size_t)(bm + wave * 32 + srow) * DIM + schk * 8;
  const __bf16* xl_g = xl + (size_t)(bm + wave * 32 + srow) * DIM + schk * 8;
  const __bf16* bh_g = WTh + (size_t)(bn + wave * 32 + srow) * DIM + schk * 8;
  const __bf16* bl_g = WTl + (size_t)(bn + wave * 32 + srow) * DIM + schk * 8;
  const int wb = wave * 2048;  // byte offset of this wave's 32 rows

  auto issue = [&](char* buf, int k0) {
    ld_lds16(buf + wb,                 xh_g + k0);
    ld_lds16(buf + wb + 1024,          xh_g + k0 + 16 * DIM);
    ld_lds16(buf + 16384 + wb,         bh_g + k0);
    ld_lds16(buf + 16384 + wb + 1024,  bh_g + k0 + 16 * DIM);
    if (kind < 2) {
      ld_lds16(buf + 8192 + wb,          xl_g + k0);
      ld_lds16(buf + 8192 + wb + 1024,   xl_g + k0 + 16 * DIM);
      ld_lds16(buf + 24576 + wb,         bl_g + k0);
      ld_lds16(buf + 24576 + wb + 1024,  bl_g + k0 + 16 * DIM);
    }
  };

  const int swz = (quad ^ (lq & 3)) * 8;

  f32x4 acc[4][4];
#pragma unroll
  for (int i = 0; i < 4; ++i)
#pragma unroll
    for (int j = 0; j < 4; ++j) acc[i][j] = (f32x4){0.f, 0.f, 0.f, 0.f};

  char* bufA = smem;
  char* bufB = smem + 32768;
  issue(bufA, 0);
  __syncthreads();
  for (int k0 = 0; k0 < DIM; k0 += 32) {
    char* cur = ((k0 >> 5) & 1) ? bufB : bufA;
    char* nxt = ((k0 >> 5) & 1) ? bufA : bufB;
    if (k0 + 32 < DIM) issue(nxt, k0 + 32);

    const __bf16* Xhs = (const __bf16*)cur;
    const __bf16* Xls = (const __bf16*)(cur + 8192);
    const __bf16* Bhs = (const __bf16*)(cur + 16384);
    const __bf16* Bls = (const __bf16*)(cur + 24576);

    bf16x8 ah[4], al[4];
#pragma unroll
    for (int i = 0; i < 4; ++i) {
      const int off = (wm + i * 16 + lq) * 32 + swz;
      ah[i] = *(const bf16x8*)&Xhs[off];
      if (kind < 2) al[i] = *(const bf16x8*)&Xls[off];
    }
#pragma unroll
    for (int j = 0; j < 4; ++j) {
      const int boff = (wn + j * 16 + lq) * 32 + swz;
      bf16x8 bh = *(const bf16x8*)&Bhs[boff];
      if (kind < 2) {
        bf16x8 bl = *(const bf16x8*)&Bls[boff];
#pragma unroll
        for (int i = 0; i < 4; ++i) {
          acc[i][j] = MFMA_BF16(ah[i], bh, acc[i][j]);
          acc[i][j] = MFMA_BF16(al[i], bh, acc[i][j]);
          acc[i][j] = MFMA_BF16(ah[i], bl, acc[i][j]);
        }
      } else {
#pragma unroll
        for (int i = 0; i < 4; ++i) acc[i][j] = MFMA_BF16(ah[i], bh, acc[i][j]);
      }
    }
    __syncthreads();
  }

  if (kind == 0) {  // q transposed, hi/lo, 8B vector stores
#pragma unroll
    for (int i = 0; i < 4; ++i)
#pragma unroll
      for (int j = 0; j < 4; ++j) {
        const int col = bn + wn + j * 16 + lq;
        const int token = bm + wm + i * 16 + quad * 4;
        bf16x4 h4, l4;
#pragma unroll
        for (int r = 0; r < 4; ++r) {
          __bf16 h, l;
          split_bf16(acc[i][j][r], h, l);
          h4[r] = h; l4[r] = l;
        }
        *(bf16x4*)(qTh + (size_t)col * MROWS + token) = h4;
        *(bf16x4*)(qTl + (size_t)col * MROWS + token) = l4;
      }
  } else if (kind == 1) {
#pragma unroll
    for (int i = 0; i < 4; ++i)
#pragma unroll
      for (int j = 0; j < 4; ++j) {
        const int col = (bn - 1024) + wn + j * 16 + lq;
#pragma unroll
        for (int r = 0; r < 4; ++r) {
          const int row = bm + wm + i * 16 + quad * 4 + r;
          __bf16 h, l;
          split_bf16(acc[i][j][r], h, l);
          KH[(size_t)row * 1024 + col] = h;
          KL[(size_t)row * 1024 + col] = l;
        }
      }
  } else {  // v -> vT[b][h][d][n] fp16
#pragma unroll
    for (int i = 0; i < 4; ++i)
#pragma unroll
      for (int j = 0; j < 4; ++j) {
        const int c = (bn - 2048) + wn + j * 16 + lq;
        const int row0 = bm + wm + i * 16 + quad * 4;
        const int b = row0 >> 11, n = row0 & 2047;
        const int h = c >> 6, d = c & 63;
        half4 o;
#pragma unroll
        for (int r = 0; r < 4; ++r) o[r] = (_Float16)acc[i][j][r];
        *(half4*)(VT + ((size_t)(b * 16 + h) * 64 + d) * 2048 + n) = o;
      }
  }
}

// ---------------------------------------------------------------------------
// Flash attention: TI=128 (4 waves x 32 q-rows), TJ=64, double-buffered LDS
// (2 x 24KB), ONE barrier per key-iter. S^T = K.Q^T (3-product bf16),
// softmax in regs, O^T = V^T.P^T (f16 K16, P^T direct from C-layout).
// ---------------------------------------------------------------------------
__global__ __launch_bounds__(256, 3) void attn5(
    const __bf16* __restrict__ qTh, const __bf16* __restrict__ qTl,
    const __bf16* __restrict__ kh, const __bf16* __restrict__ kl,
    const _Float16* __restrict__ vT, _Float16* __restrict__ ho) {
  __shared__ __align__(16) char smem[49152];  // 2 bufs: Kh 8K | Kl 8K | Vt 8K
  const int t = threadIdx.x;
  const int lane = t & 63, wave = t >> 6, quad = lane >> 4, lq = lane & 15;
  const int i0 = blockIdx.x * 128;
  const int bh = blockIdx.y, b = bh >> 4, head = bh & 15;
  const size_t rowbase = (size_t)b * NSEQ;

  // Q fragments (B-operand layout) from transposed q
  bf16x8 qfh[2][2], qfl[2][2];
#pragma unroll
  for (int qt = 0; qt < 2; ++qt) {
    const size_t tok = rowbase + i0 + wave * 32 + qt * 16 + lq;
#pragma unroll
    for (int hf = 0; hf < 2; ++hf)
#pragma unroll
      for (int jj = 0; jj < 8; ++jj) {
        const size_t c = (size_t)(head * 64 + hf * 32 + quad * 8 + jj) * MROWS + tok;
        qfh[qt][hf][jj] = qTh[c];
        qfl[qt][hf][jj] = qTl[c];
      }
  }

  f32x4 o[2][4];
#pragma unroll
  for (int qt = 0; qt < 2; ++qt)
#pragma unroll
    for (int dt = 0; dt < 4; ++dt) o[qt][dt] = (f32x4){0.f, 0.f, 0.f, 0.f};
  float mrun[2] = {-3.0e38f, -3.0e38f};
  float lrun[2] = {0.f, 0.f};

  const int srow = lane >> 3, schk = (lane & 7) ^ srow;
  const __bf16* khg = kh + (rowbase + wave * 16 + srow) * DIM + head * 64 + schk * 8;
  const __bf16* klg = kl + (rowbase + wave * 16 + srow) * DIM + head * 64 + schk * 8;
  const _Float16* vg = vT + ((size_t)bh * 64 + wave * 16 + srow) * NSEQ + schk * 8;
  const int wb = wave * 2048;

  auto issue = [&](char* buf, int j0) {
    const size_t ko = (size_t)j0 * DIM;
    ld_lds16(buf + wb,                 khg + ko);
    ld_lds16(buf + wb + 1024,          khg + ko + 8 * DIM);
    ld_lds16(buf + 8192 + wb,          klg + ko);
    ld_lds16(buf + 8192 + wb + 1024,   klg + ko + 8 * DIM);
    ld_lds16(buf + 16384 + wb,         vg + j0);
    ld_lds16(buf + 16384 + wb + 1024,  vg + j0 + 8 * NSEQ);
  };

  const int swzK0 = (quad ^ (lq & 7)) * 8;
  const int swzK1 = ((quad + 4) ^ (lq & 7)) * 8;

  char* bufA = smem;
  char* bufB = smem + 24576;
  issue(bufA, 0);
  __syncthreads();

  for (int j0 = 0; j0 < NSEQ; j0 += 64) {
    char* cur = ((j0 >> 6) & 1) ? bufB : bufA;
    char* nxt = ((j0 >> 6) & 1) ? bufA : bufB;
    if (j0 + 64 < NSEQ) issue(nxt, j0 + 64);

    const __bf16* Khs = (const __bf16*)cur;
    const __bf16* Kls = (const __bf16*)(cur + 8192);
    const _Float16* Vts = (const _Float16*)(cur + 16384);

    // S^T = K.Q^T
    f32x4 s[2][4];
#pragma unroll
    for (int nt = 0; nt < 4; ++nt) {
      const int roff = (nt * 16 + lq) * 64;
      bf16x8 k0f = *(const bf16x8*)&Khs[roff + swzK0];
      bf16x8 k1f = *(const bf16x8*)&Khs[roff + swzK1];
      bf16x8 l0f = *(const bf16x8*)&Kls[roff + swzK0];
      bf16x8 l1f = *(const bf16x8*)&Kls[roff + swzK1];
#pragma unroll
      for (int qt = 0; qt < 2; ++qt) {
        f32x4 sv = (f32x4){0.f, 0.f, 0.f, 0.f};
        sv = MFMA_BF16(k0f, qfh[qt][0], sv);
        sv = MFMA_BF16(k1f, qfh[qt][1], sv);
        sv = MFMA_BF16(k0f, qfl[qt][0], sv);
        sv = MFMA_BF16(k1f, qfl[qt][1], sv);
        sv = MFMA_BF16(l0f, qfh[qt][0], sv);
        sv = MFMA_BF16(l1f, qfh[qt][1], sv);
        s[qt][nt] = sv;
      }
    }

    // online softmax (rows lane-resident; 2 shuffles per reduction)
    half4 pb[2][4];
#pragma unroll
    for (int qt = 0; qt < 2; ++qt) {
      float mx = s[qt][0][0];
#pragma unroll
      for (int nt = 0; nt < 4; ++nt)
#pragma unroll
        for (int r = 0; r < 4; ++r) mx = fmaxf(mx, s[qt][nt][r]);
      mx = fmaxf(mx, __shfl_xor(mx, 16));
      mx = fmaxf(mx, __shfl_xor(mx, 32));
      const float mn = fmaxf(mrun[qt], mx);
      const float alpha = EXP2F(mrun[qt] - mn);
      mrun[qt] = mn;
      float rs = 0.f;
#pragma unroll
      for (int nt = 0; nt < 4; ++nt)
#pragma unroll
        for (int r = 0; r < 4; ++r) {
          float p = EXP2F(s[qt][nt][r] - mn);
          rs += p;
          pb[qt][nt][r] = (_Float16)p;
        }
      rs += __shfl_xor(rs, 16);
      rs += __shfl_xor(rs, 32);
      lrun[qt] = lrun[qt] * alpha + rs;
#pragma unroll
      for (int dt = 0; dt < 4; ++dt) o[qt][dt] *= alpha;
    }

    // O^T += V^T . P^T
#pragma unroll
    for (int dt = 0; dt < 4; ++dt) {
      const int vrow = (dt * 16 + lq) * 64;
#pragma unroll
      for (int nt = 0; nt < 4; ++nt) {
        const int chk = (nt * 2 + (quad >> 1)) ^ (lq & 7);
        half4 va = *(const half4*)&Vts[vrow + chk * 8 + (quad & 1) * 4];
        o[0][dt] = MFMA_F16K16(va, pb[0][nt], o[0][dt]);
        o[1][dt] = MFMA_F16K16(va, pb[1][nt], o[1][dt]);
      }
    }
    __syncthreads();
  }

  // epilogue: O^T -> LDS transpose (pitch 80 f16, 16B-aligned rows) -> store
  _Float16* Ots = (_Float16*)smem;
#pragma unroll
  for (int qt = 0; qt < 2; ++qt) {
    const float inv = 1.0f / lrun[qt];
#pragma unroll
    for (int dt = 0; dt < 4; ++dt)
#pragma unroll
      for (int r = 0; r < 4; ++r)
        Ots[(wave * 32 + qt * 16 + lq) * 80 + dt * 16 + quad * 4 + r] =
            (_Float16)(o[qt][dt][r] * inv);
  }
  __syncthreads();
  {
    const int row = t >> 1, hf = t & 1;
    const _Float16* src = &Ots[row * 80 + hf * 32];
    half8 o0 = ((const half8*)src)[0], o1 = ((const half8*)src)[1],
          o2 = ((const half8*)src)[2], o3 = ((const half8*)src)[3];
    _Float16* dst = ho + (rowbase + i0 + row) * DIM + head * 64 + hf * 32;
    ((half8*)dst)[0] = o0; ((half8*)dst)[1] = o1;
    ((half8*)dst)[2] = o2; ((half8*)dst)[3] = o3;
  }
}

// ---------------------------------------------------------------------------
// out = ho(fp16) @ w_out — double-buffered, one barrier per K-iter.
// ---------------------------------------------------------------------------
__global__ __launch_bounds__(256, 4) void gemm_out(
    const _Float16* __restrict__ A, const _Float16* __restrict__ BT,
    float* __restrict__ C) {
  __shared__ __align__(16) char smem[24576];  // 2 bufs: A 4KB | B 8KB
  const int t = threadIdx.x;
  const int lane = t & 63, wave = t >> 6, quad = lane >> 4, lq = lane & 15;
  const int bn = blockIdx.x * 128, bm = blockIdx.y * 64;
  const int wm = (wave >> 1) * 32, wn = (wave & 1) * 64;

  const int bco = (lane & 7) ^ (lane >> 3);
  const int brow = 2 * (lane >> 3) + (bco >> 2);
  const int bcc = bco & 3;
  const _Float16* ag = A + (size_t)(bm + wave * 16 + brow) * DIM + bcc * 8;
  const _Float16* bg = BT + (size_t)(bn + wave * 32 + brow) * DIM + bcc * 8;
  const int swzB = ((((lq & 1) << 2) | quad) ^ ((lq >> 1) & 7)) * 8;

  auto issue = [&](char* buf, int k0) {
    ld_lds16(buf + wave * 1024,               ag + k0);
    ld_lds16(buf + 4096 + wave * 2048,        bg + k0);
    ld_lds16(buf + 4096 + wave * 2048 + 1024, bg + k0 + 16 * DIM);
  };

  f32x4 acc[2][4];
#pragma unroll
  for (int i = 0; i < 2; ++i)
#pragma unroll
    for (int j = 0; j < 4; ++j) acc[i][j] = (f32x4){0.f, 0.f, 0.f, 0.f};

  char* bufA = smem;
  char* bufB = smem + 12288;
  issue(bufA, 0);
  __syncthreads();
  for (int k0 = 0; k0 < DIM; k0 += 32) {
    char* cur = ((k0 >> 5) & 1) ? bufB : bufA;
    char* nxt = ((k0 >> 5) & 1) ? bufA : bufB;
    if (k0 + 32 < DIM) issue(nxt, k0 + 32);
    const _Float16* Ahs = (const _Float16*)cur;
    const _Float16* Bhs = (const _Float16*)(cur + 4096);
    half8 ah[2];
#pragma unroll
    for (int i = 0; i < 2; ++i) {
      const int row = wm + i * 16 + lq;
      ah[i] = *(const half8*)&Ahs[(row >> 1) * 64 + swzB];
    }
#pragma unroll
    for (int j = 0; j < 4; ++j) {
      const int row = wn + j * 16 + lq;
      half8 bh = *(const half8*)&Bhs[(row >> 1) * 64 + swzB];
#pragma unroll
      for (int i = 0; i < 2; ++i) acc[i][j] = MFMA_F16K32(ah[i], bh, acc[i][j]);
    }
    __syncthreads();
  }
#pragma unroll
  for (int i = 0; i < 2; ++i)
#pragma unroll
    for (int j = 0; j < 4; ++j) {
      const int col = bn + wn + j * 16 + lq;
#pragma unroll
      for (int r = 0; r < 4; ++r) {
        const int row = bm + wm + i * 16 + quad * 4 + r;
        C[(size_t)row * 1024 + col] = acc[i][j][r];
      }
    }
}

// ---------------------------------------------------------------------------
extern "C" void kernel_launch(void* const* d_in, const int* in_sizes, int n_in,
                              void* d_out, int out_size, void* d_ws,
                              size_t ws_size, hipStream_t stream) {
  const float* x     = (const float*)d_in[0];
  const float* w_q   = (const float*)d_in[1];
  const float* w_vk  = (const float*)d_in[2];
  const float* w_out = (const float*)d_in[3];
  float* out = (float*)d_out;

  char* w = (char*)d_ws;  // 60 MB used
  __bf16*   wTh = (__bf16*)(w);                   // [3072][1024] 6MB
  __bf16*   wTl = (__bf16*)(w + (6ull << 20));    // [2048][1024] 4MB
  _Float16* woT = (_Float16*)(w + (10ull << 20)); // [1024][1024] 2MB
  __bf16*   qTh = (__bf16*)(w + (12ull << 20));   // [1024][4096] 8MB each
  __bf16*   qTl = (__bf16*)(w + (20ull << 20));
  __bf16*   khb = (__bf16*)(w + (28ull << 20));   // [4096][1024]
  __bf16*   klb = (__bf16*)(w + (36ull << 20));
  _Float16* vTb = (_Float16*)(w + (44ull << 20)); // [b][h][64][2048]
  _Float16* hob = (_Float16*)(w + (52ull << 20)); // [4096][1024]

  // x hi/lo split lives in d_out (dead until gemm_out writes it)
  __bf16* xh = (__bf16*)d_out;
  __bf16* xl = xh + (size_t)MROWS * DIM;

  dim3 blk(256);
  prep<<<dim3(3072), blk, 0, stream>>>(w_q, w_vk, w_out, x, wTh, wTl, woT, xh, xl);
  proj5<<<dim3(24, 32), blk, 0, stream>>>(
      xh, xl, wTh, wTl, qTh, qTl, khb, klb, vTb);
  attn5<<<dim3(16, 32), blk, 0, stream>>>(qTh, qTl, khb, klb, vTb, hob);
  gemm_out<<<dim3(8, 64), blk, 0, stream>>>(hob, woT, out);
}